// Round 16
// baseline (90.452 us; speedup 1.0000x reference)
//
#include <hip/hip_runtime.h>

// GCN layer: out = ReLU(x @ U^T + segment_sum(x[src], dst) @ V^T)
// x: [50000, 64] f32, src/dst: [1M] i32, U/V: [64, 64] f32, out: [50000, 64] f32
//
// Round 16: r15 pipeline with the gather's edge-pairing widened to 4 edges
// per wave-load (4 lane-groups x 16 lanes x dwordx2 = 4 rows/load):
// VMEM wave-instructions 10 -> 5 per node, 1 index-shuffle per 4 edges.
// Build unchanged (binA 256-bucket chunked writes + sortB counting sort).

constexpr int N_NODES = 50000;
constexpr int N_EDGES = 1000000;
constexpr int D = 64;

constexpr int BSH  = 8;                                   // 256-node buckets
constexpr int NPB2 = 1 << BSH;                            // 256
constexpr int NBK  = (N_NODES + NPB2 - 1) >> BSH;         // 196
constexpr int CAPB = 5888;                                // mean 5102, +11 sigma
constexpr int TILE = 4096;                                // pass-A edges/block
constexpr int ABLK = (N_EDGES + TILE - 1) / TILE;         // 245
constexpr int CVT_BLOCKS = (N_NODES * D / 4) / 256;       // 3125
constexpr int CAP = 64;                                   // fallback bucket cap

// ---------------------------------------------------------------------------
// Pass A (+ fused cvt): blocks [0,ABLK) bin edges into 196 buckets with
// chunk-reserved coalesced writes; blocks [ABLK,..) convert x -> fp16.
// gbuf entry = (b<<24) | (dst&255)<<16 | src.  cursor stride 16 ints.
// ---------------------------------------------------------------------------
__global__ __launch_bounds__(256) void binA_cvt_kernel(
    const float* __restrict__ x, _Float16* __restrict__ xh,
    const int* __restrict__ src, const int* __restrict__ dst,
    int* __restrict__ cursor, unsigned int* __restrict__ gbuf)
{
    const int bid = blockIdx.x;
    if (bid >= ABLK) {
        const int i = ((bid - ABLK) * 256 + threadIdx.x) * 4;
        const float4 v = *reinterpret_cast<const float4*>(x + i);
        union { _Float16 h[4]; unsigned long long u; } p;
        p.h[0] = (_Float16)v.x;
        p.h[1] = (_Float16)v.y;
        p.h[2] = (_Float16)v.z;
        p.h[3] = (_Float16)v.w;
        *reinterpret_cast<unsigned long long*>(xh + i) = p.u;
        return;
    }

    __shared__ int cnt[NBK];            // histogram, then rank cursor
    __shared__ int base[NBK + 1];
    __shared__ int delta[NBK];
    __shared__ int sc[256];
    __shared__ unsigned int stage[TILE];

    const int t = threadIdx.x;
    const int e0 = bid * TILE;
    const int e1 = (e0 + TILE < N_EDGES) ? e0 + TILE : N_EDGES;
    const int n  = e1 - e0;

    if (t < NBK) cnt[t] = 0;
    __syncthreads();

    for (int i = e0 + t; i < e1; i += 256)
        atomicAdd(&cnt[dst[i] >> BSH], 1);
    __syncthreads();

    // 256-wide exclusive scan of cnt -> base
    const int l = (t < NBK) ? cnt[t] : 0;
    sc[t] = l;
    __syncthreads();
    for (int off = 1; off < 256; off <<= 1) {
        const int u = (t >= off) ? sc[t - off] : 0;
        __syncthreads();
        sc[t] += u;
        __syncthreads();
    }
    if (t < NBK) base[t] = sc[t] - l;
    if (t == 255) base[NBK] = sc[255];
    __syncthreads();

    // reserve global chunks; write deltas; reset rank cursors
    if (t < NBK) {
        const int g = atomicAdd(&cursor[t * 16], l);
        delta[t] = t * CAPB + g - base[t];
    }
    __syncthreads();
    if (t < NBK) cnt[t] = base[t];
    __syncthreads();

    for (int i = e0 + t; i < e1; i += 256) {
        const int d = dst[i], s = src[i];
        const int b = d >> BSH;
        const int slot = atomicAdd(&cnt[b], 1);
        stage[slot] = ((unsigned)b << 24) | ((unsigned)(d & (NPB2 - 1)) << 16)
                    | (unsigned)s;
    }
    __syncthreads();

    for (int i = t; i < n; i += 256) {
        const unsigned v = stage[i];
        const int b = (int)(v >> 24);
        const int addr = delta[b] + i;
        if (addr < (b + 1) * CAPB) gbuf[addr] = v;   // chunked coalesced runs
    }
}

// ---------------------------------------------------------------------------
// Pass B: one 1024-thr block per bucket (196); LDS counting sort by
// dst-within-bucket. Sequential writes: sorted u16 src list + rs/deg.
// ---------------------------------------------------------------------------
__global__ __launch_bounds__(1024) void sortB_kernel(
    const int* __restrict__ cursor, const unsigned int* __restrict__ gbuf,
    unsigned short* __restrict__ esrc, int* __restrict__ rs,
    int* __restrict__ deg)
{
    __shared__ int hist[NPB2];
    __shared__ int sc[NPB2];
    __shared__ unsigned short sorted[CAPB];

    const int b = blockIdx.x, t = threadIdx.x;
    int cntE = cursor[b * 16];
    cntE = (cntE > CAPB) ? CAPB : cntE;
    const int gb = b * CAPB;

    if (t < NPB2) hist[t] = 0;
    __syncthreads();
    for (int i = t; i < cntE; i += 1024)
        atomicAdd(&hist[(gbuf[gb + i] >> 16) & (NPB2 - 1)], 1);
    __syncthreads();

    int hv = 0;
    if (t < NPB2) { hv = hist[t]; sc[t] = hv; }
    __syncthreads();
    for (int off = 1; off < NPB2; off <<= 1) {
        int u = 0;
        if (t < NPB2 && t >= off) u = sc[t - off];
        __syncthreads();
        if (t < NPB2) sc[t] += u;
        __syncthreads();
    }
    if (t < NPB2) {
        const int excl = sc[t] - hv;
        const int node = (b << BSH) + t;
        if (node < N_NODES) { rs[node] = gb + excl; deg[node] = hv; }
        hist[t] = excl;                 // rank cursor
    }
    __syncthreads();

    for (int i = t; i < cntE; i += 1024) {
        const unsigned v = gbuf[gb + i];
        const int slot = atomicAdd(&hist[(v >> 16) & (NPB2 - 1)], 1);
        sorted[slot] = (unsigned short)(v & 0xFFFFu);
    }
    __syncthreads();

    for (int i = t; i < cntE; i += 1024) esrc[gb + i] = sorted[i];
}

// ---------------------------------------------------------------------------
// Gather + dual-GEMM + ReLU (r13 structure + 4-edge dwordx2 pairing).
// 512 thr = 8 waves share one Ut/Vt; wave per node.
// Lane-groups of 16 (g4 = o>>4) take edges j+g4; each lane loads 8B =
// 4 fp16 features -> one wave-load covers 4 rows. Merge: shfl_xor(16,32).
// ---------------------------------------------------------------------------
__global__ __launch_bounds__(512, 8) void gather_gemm_f16_kernel(
    const float* __restrict__ x, const _Float16* __restrict__ xh,
    const int* __restrict__ rs, const int* __restrict__ deg,
    const unsigned short* __restrict__ esrc,
    const float* __restrict__ U, const float* __restrict__ V,
    float* __restrict__ out)
{
    __shared__ float Ut[D][D + 1];
    __shared__ float Vt[D][D + 1];
    __shared__ float rows[8][2][D];

    const int t = threadIdx.x, o = t & 63, w = t >> 6;

    for (int i = t; i < D * D; i += 512) {
        Ut[i & 63][i >> 6] = U[i];
        Vt[i & 63][i >> 6] = V[i];
    }
    __syncthreads();

    const int n = blockIdx.x * 8 + w;   // grid exactly N_NODES/8
    const int rowoff = n * D + o;

    rows[w][0][o] = x[rowoff];

    const int beg = rs[n];
    int dg = deg[n];
    dg = (dg > 64) ? 64 : dg;
    const int vidx = (int)esrc[beg + ((o < dg) ? o : 0)];

    const int g4  = o >> 4;             // edge group 0..3
    const int fo4 = (o & 15) * 4;       // feature quad base

    union H4 { unsigned long long u; _Float16 h[4]; };
    float a0 = 0.f, a1 = 0.f, a2 = 0.f, a3 = 0.f;

    int j = 0;
    for (; j + 16 <= dg; j += 16) {     // 4 independent 4-row wave-loads
        const int sA = __shfl(vidx, j + 0  + g4);
        const int sB = __shfl(vidx, j + 4  + g4);
        const int sC = __shfl(vidx, j + 8  + g4);
        const int sD = __shfl(vidx, j + 12 + g4);
        H4 pA, pB, pC, pD;
        pA.u = *reinterpret_cast<const unsigned long long*>(xh + sA * D + fo4);
        pB.u = *reinterpret_cast<const unsigned long long*>(xh + sB * D + fo4);
        pC.u = *reinterpret_cast<const unsigned long long*>(xh + sC * D + fo4);
        pD.u = *reinterpret_cast<const unsigned long long*>(xh + sD * D + fo4);
        a0 += ((float)pA.h[0] + (float)pB.h[0])
            + ((float)pC.h[0] + (float)pD.h[0]);
        a1 += ((float)pA.h[1] + (float)pB.h[1])
            + ((float)pC.h[1] + (float)pD.h[1]);
        a2 += ((float)pA.h[2] + (float)pB.h[2])
            + ((float)pC.h[2] + (float)pD.h[2]);
        a3 += ((float)pA.h[3] + (float)pB.h[3])
            + ((float)pC.h[3] + (float)pD.h[3]);
    }
    for (; j + 4 <= dg; j += 4) {       // 4-edge steps
        const int s = __shfl(vidx, j + g4);
        H4 p;
        p.u = *reinterpret_cast<const unsigned long long*>(xh + s * D + fo4);
        a0 += (float)p.h[0];
        a1 += (float)p.h[1];
        a2 += (float)p.h[2];
        a3 += (float)p.h[3];
    }
    for (; j < dg; ++j) {               // tail 0..3 edges, group-0 lanes
        const int s = __shfl(vidx, j);
        if (o < 16) {
            H4 p;
            p.u = *reinterpret_cast<const unsigned long long*>(xh + s * D + fo4);
            a0 += (float)p.h[0];
            a1 += (float)p.h[1];
            a2 += (float)p.h[2];
            a3 += (float)p.h[3];
        }
    }
    a0 += __shfl_xor(a0, 16); a0 += __shfl_xor(a0, 32);
    a1 += __shfl_xor(a1, 16); a1 += __shfl_xor(a1, 32);
    a2 += __shfl_xor(a2, 16); a2 += __shfl_xor(a2, 32);
    a3 += __shfl_xor(a3, 16); a3 += __shfl_xor(a3, 32);
    if (o < 16) {
        float4 r;
        r.x = a0; r.y = a1; r.z = a2; r.w = a3;
        *reinterpret_cast<float4*>(&rows[w][1][fo4]) = r;
    }
    // wave-private LDS rows: in-wave ordering, no block barrier needed.

    float sum = 0.f;
    #pragma unroll
    for (int k4 = 0; k4 < D / 4; ++k4) {
        const int k = k4 * 4;
        const float4 xq = *reinterpret_cast<const float4*>(&rows[w][0][k]);
        const float4 aq = *reinterpret_cast<const float4*>(&rows[w][1][k]);
        sum += xq.x * Ut[k + 0][o] + aq.x * Vt[k + 0][o];
        sum += xq.y * Ut[k + 1][o] + aq.y * Vt[k + 1][o];
        sum += xq.z * Ut[k + 2][o] + aq.z * Vt[k + 2][o];
        sum += xq.w * Ut[k + 3][o] + aq.w * Vt[k + 3][o];
    }
    out[rowoff] = fmaxf(sum, 0.f);
}

// ---------------------------------------------------------------------------
// Mid fallback (r12): 64-cap bucket fill + f32 gather.
// ---------------------------------------------------------------------------
__global__ __launch_bounds__(256) void fill_only_kernel(
    const int* __restrict__ src, const int* __restrict__ dst,
    int* __restrict__ deg, unsigned short* __restrict__ esrc)
{
    const int e = blockIdx.x * 256 + threadIdx.x;
    if (e < N_EDGES) {
        const int d = dst[e];
        const int s = src[e];
        const int sl = atomicAdd(&deg[d], 1);
        if (sl < CAP) esrc[(d << 6) + sl] = (unsigned short)s;
    }
}

__global__ __launch_bounds__(512, 8) void bucket_gather_gemm_kernel(
    const float* __restrict__ x, const int* __restrict__ deg,
    const unsigned short* __restrict__ esrc,
    const float* __restrict__ U, const float* __restrict__ V,
    float* __restrict__ out)
{
    __shared__ float Ut[D][D + 1];
    __shared__ float Vt[D][D + 1];
    __shared__ float rows[8][2][D];

    const int t = threadIdx.x, o = t & 63, w = t >> 6;

    for (int i = t; i < D * D; i += 512) {
        Ut[i & 63][i >> 6] = U[i];
        Vt[i & 63][i >> 6] = V[i];
    }
    __syncthreads();

    const int n = blockIdx.x * 8 + w;
    const int rowoff = n * D + o;
    rows[w][0][o] = x[rowoff];

    int dg = deg[n];
    dg = (dg > CAP) ? CAP : dg;
    const int vidx = (int)esrc[(n << 6) + ((o < dg) ? o : 0)];

    float acc = 0.f;
    int j = 0;
    for (; j + 4 <= dg; j += 4) {
        const int s0 = __shfl(vidx, j + 0), s1 = __shfl(vidx, j + 1);
        const int s2 = __shfl(vidx, j + 2), s3 = __shfl(vidx, j + 3);
        acc += x[s0 * D + o] + x[s1 * D + o] + x[s2 * D + o] + x[s3 * D + o];
    }
    for (; j < dg; ++j) {
        const int s = __shfl(vidx, j);
        acc += x[s * D + o];
    }
    rows[w][1][o] = acc;

    float sum = 0.f;
    #pragma unroll
    for (int k4 = 0; k4 < D / 4; ++k4) {
        const int k = k4 * 4;
        const float4 xq = *reinterpret_cast<const float4*>(&rows[w][0][k]);
        const float4 aq = *reinterpret_cast<const float4*>(&rows[w][1][k]);
        sum += xq.x * Ut[k + 0][o] + aq.x * Vt[k + 0][o];
        sum += xq.y * Ut[k + 1][o] + aq.y * Vt[k + 1][o];
        sum += xq.z * Ut[k + 2][o] + aq.z * Vt[k + 2][o];
        sum += xq.w * Ut[k + 3][o] + aq.w * Vt[k + 3][o];
    }
    out[rowoff] = fmaxf(sum, 0.f);
}

// ---------------------------------------------------------------------------
// Last-resort fallback: atomic scatter + separate GEMM (no ws needed).
// ---------------------------------------------------------------------------
__global__ __launch_bounds__(256) void scatter_add_kernel(
    const float* __restrict__ x, const int* __restrict__ src,
    const int* __restrict__ dst, float* agg)
{
    const int tid = blockIdx.x * 256 + threadIdx.x;
    const int e = tid >> 4;
    const int qq = (tid & 15) << 2;
    const int s = src[e];
    const int d = dst[e];
    const float4 v = *reinterpret_cast<const float4*>(x + s * D + qq);
    float* a = agg + d * D + qq;
    unsafeAtomicAdd(a + 0, v.x);
    unsafeAtomicAdd(a + 1, v.y);
    unsafeAtomicAdd(a + 2, v.z);
    unsafeAtomicAdd(a + 3, v.w);
}

__global__ __launch_bounds__(256) void gemm_relu_kernel(
    const float* __restrict__ x, const float* agg,
    const float* __restrict__ U, const float* __restrict__ V,
    float* out)
{
    __shared__ float Ut[D][D + 1];
    __shared__ float Vt[D][D + 1];
    __shared__ float xs[4][D][4];
    __shared__ float as[4][D][4];

    const int t = threadIdx.x, o = t & 63, w = t >> 6;

    for (int i = t; i < D * D; i += 256) {
        Ut[i & 63][i >> 6] = U[i];
        Vt[i & 63][i >> 6] = V[i];
    }
    __syncthreads();

    const int nb = blockIdx.x * 16 + w * 4;
    #pragma unroll
    for (int j = 0; j < 4; ++j) {
        const int n = nb + j;
        xs[w][o][j] = x[n * D + o];
        as[w][o][j] = agg[n * D + o];
    }

    float acc0 = 0.f, acc1 = 0.f, acc2 = 0.f, acc3 = 0.f;
    #pragma unroll 16
    for (int k = 0; k < D; ++k) {
        const float u = Ut[k][o];
        const float v = Vt[k][o];
        const float4 xv = *reinterpret_cast<const float4*>(&xs[w][k][0]);
        const float4 av = *reinterpret_cast<const float4*>(&as[w][k][0]);
        acc0 += u * xv.x + v * av.x;
        acc1 += u * xv.y + v * av.y;
        acc2 += u * xv.z + v * av.z;
        acc3 += u * xv.w + v * av.w;
    }

    out[(nb + 0) * D + o] = fmaxf(acc0, 0.f);
    out[(nb + 1) * D + o] = fmaxf(acc1, 0.f);
    out[(nb + 2) * D + o] = fmaxf(acc2, 0.f);
    out[(nb + 3) * D + o] = fmaxf(acc3, 0.f);
}

extern "C" void kernel_launch(void* const* d_in, const int* in_sizes, int n_in,
                              void* d_out, int out_size, void* d_ws, size_t ws_size,
                              hipStream_t stream) {
    const float* x   = (const float*)d_in[0];
    const int*   src = (const int*)d_in[1];
    const int*   dst = (const int*)d_in[2];
    const float* U   = (const float*)d_in[3];
    const float* V   = (const float*)d_in[4];
    float* out = (float*)d_out;

    // full ws layout (int units):
    //   cursor [196*16] | gbuf u32 [196*5888] | rs [50000] | deg [50000] |
    //   esrc u16 [196*5888] | xh fp16 [3.2M]              (~13.7 MiB)
    const size_t cur_off = 0;
    const size_t gb_off  = (size_t)NBK * 16;
    const size_t rs_off  = gb_off + (size_t)NBK * CAPB;
    const size_t dg_off  = rs_off + N_NODES;
    const size_t es_off  = dg_off + N_NODES;
    const size_t xh_off  = es_off + (size_t)NBK * CAPB / 2;
    const size_t full_bytes = (xh_off + (size_t)N_NODES * D / 2) * sizeof(int);

    // mid (r12) layout: deg[50000] | esrc u16[50000*64]
    const size_t m_es_off = (size_t)N_NODES;
    const size_t mid_bytes = (m_es_off + (size_t)N_NODES * CAP / 2) * sizeof(int);

    if (ws_size >= full_bytes) {
        int* wsi = (int*)d_ws;
        int* cursor = wsi + cur_off;
        unsigned int* gbuf = (unsigned int*)(wsi + gb_off);
        int* rs  = wsi + rs_off;
        int* deg = wsi + dg_off;
        unsigned short* esrc = (unsigned short*)(wsi + es_off);
        _Float16* xh = (_Float16*)(wsi + xh_off);

        hipMemsetAsync(cursor, 0, (size_t)NBK * 16 * sizeof(int), stream);
        binA_cvt_kernel<<<ABLK + CVT_BLOCKS, 256, 0, stream>>>(
            x, xh, src, dst, cursor, gbuf);
        sortB_kernel<<<NBK, 1024, 0, stream>>>(cursor, gbuf, esrc, rs, deg);
        gather_gemm_f16_kernel<<<N_NODES / 8, 512, 0, stream>>>(
            x, xh, rs, deg, esrc, U, V, out);
    } else if (ws_size >= mid_bytes) {
        int* wsi = (int*)d_ws;
        int* deg = wsi;
        unsigned short* esrc = (unsigned short*)(wsi + m_es_off);

        hipMemsetAsync(deg, 0, (size_t)N_NODES * sizeof(int), stream);
        fill_only_kernel<<<(N_EDGES + 255) / 256, 256, 0, stream>>>(
            src, dst, deg, esrc);
        bucket_gather_gemm_kernel<<<N_NODES / 8, 512, 0, stream>>>(
            x, deg, esrc, U, V, out);
    } else {
        const size_t agg_bytes = (size_t)N_NODES * D * sizeof(float);
        float* agg = (ws_size >= agg_bytes) ? (float*)d_ws : out;
        hipMemsetAsync(agg, 0, agg_bytes, stream);
        scatter_add_kernel<<<(N_EDGES * 16) / 256, 256, 0, stream>>>(x, src, dst, agg);
        gemm_relu_kernel<<<N_NODES / 16, 256, 0, stream>>>(x, agg, U, V, out);
    }
}

// Round 17
// 88.098 us; speedup vs baseline: 1.0267x; 1.0267x over previous
//
#include <hip/hip_runtime.h>

// GCN layer: out = ReLU(x @ U^T + segment_sum(x[src], dst) @ V^T)
// x: [50000, 64] f32, src/dst: [1M] i32, U/V: [64, 64] f32, out: [50000, 64] f32
//
// Round 17 (= r15, the measured optimum; r16's wider pairing regressed):
//  - build: binA (256-node buckets, chunk-reserved coalesced writes, fused
//    x->fp16 cvt) + sortB (per-bucket LDS counting sort, sequential writes).
//  - gather: wave-per-node, register-resident u16 indices, half2
//    edge-pairing (lanes 0-31 edge j, 32-63 edge j+1, 4B/lane), 8-deep
//    independent loads, shfl_xor(32) merge, shared-Ut/Vt dual-GEMM epilogue.
// 87.6 us total: gather 61.4 (44 us = 44MB random-row HBM floor), build ~26.

constexpr int N_NODES = 50000;
constexpr int N_EDGES = 1000000;
constexpr int D = 64;

constexpr int BSH  = 8;                                   // 256-node buckets
constexpr int NPB2 = 1 << BSH;                            // 256
constexpr int NBK  = (N_NODES + NPB2 - 1) >> BSH;         // 196
constexpr int CAPB = 5888;                                // mean 5102, +11 sigma
constexpr int TILE = 4096;                                // pass-A edges/block
constexpr int ABLK = (N_EDGES + TILE - 1) / TILE;         // 245
constexpr int CVT_BLOCKS = (N_NODES * D / 4) / 256;       // 3125
constexpr int CAP = 64;                                   // fallback bucket cap

// ---------------------------------------------------------------------------
// Pass A (+ fused cvt): blocks [0,ABLK) bin edges into 196 buckets with
// chunk-reserved coalesced writes; blocks [ABLK,..) convert x -> fp16.
// gbuf entry = (b<<24) | (dst&255)<<16 | src.  cursor stride 16 ints.
// ---------------------------------------------------------------------------
__global__ __launch_bounds__(256) void binA_cvt_kernel(
    const float* __restrict__ x, _Float16* __restrict__ xh,
    const int* __restrict__ src, const int* __restrict__ dst,
    int* __restrict__ cursor, unsigned int* __restrict__ gbuf)
{
    const int bid = blockIdx.x;
    if (bid >= ABLK) {
        const int i = ((bid - ABLK) * 256 + threadIdx.x) * 4;
        const float4 v = *reinterpret_cast<const float4*>(x + i);
        union { _Float16 h[4]; unsigned long long u; } p;
        p.h[0] = (_Float16)v.x;
        p.h[1] = (_Float16)v.y;
        p.h[2] = (_Float16)v.z;
        p.h[3] = (_Float16)v.w;
        *reinterpret_cast<unsigned long long*>(xh + i) = p.u;
        return;
    }

    __shared__ int cnt[NBK];            // histogram, then rank cursor
    __shared__ int base[NBK + 1];
    __shared__ int delta[NBK];
    __shared__ int sc[256];
    __shared__ unsigned int stage[TILE];

    const int t = threadIdx.x;
    const int e0 = bid * TILE;
    const int e1 = (e0 + TILE < N_EDGES) ? e0 + TILE : N_EDGES;
    const int n  = e1 - e0;

    if (t < NBK) cnt[t] = 0;
    __syncthreads();

    for (int i = e0 + t; i < e1; i += 256)
        atomicAdd(&cnt[dst[i] >> BSH], 1);
    __syncthreads();

    // 256-wide exclusive scan of cnt -> base
    const int l = (t < NBK) ? cnt[t] : 0;
    sc[t] = l;
    __syncthreads();
    for (int off = 1; off < 256; off <<= 1) {
        const int u = (t >= off) ? sc[t - off] : 0;
        __syncthreads();
        sc[t] += u;
        __syncthreads();
    }
    if (t < NBK) base[t] = sc[t] - l;
    if (t == 255) base[NBK] = sc[255];
    __syncthreads();

    // reserve global chunks; write deltas; reset rank cursors
    if (t < NBK) {
        const int g = atomicAdd(&cursor[t * 16], l);
        delta[t] = t * CAPB + g - base[t];
    }
    __syncthreads();
    if (t < NBK) cnt[t] = base[t];
    __syncthreads();

    for (int i = e0 + t; i < e1; i += 256) {
        const int d = dst[i], s = src[i];
        const int b = d >> BSH;
        const int slot = atomicAdd(&cnt[b], 1);
        stage[slot] = ((unsigned)b << 24) | ((unsigned)(d & (NPB2 - 1)) << 16)
                    | (unsigned)s;
    }
    __syncthreads();

    for (int i = t; i < n; i += 256) {
        const unsigned v = stage[i];
        const int b = (int)(v >> 24);
        const int addr = delta[b] + i;
        if (addr < (b + 1) * CAPB) gbuf[addr] = v;   // chunked coalesced runs
    }
}

// ---------------------------------------------------------------------------
// Pass B: one 1024-thr block per bucket (196); LDS counting sort by
// dst-within-bucket. Sequential writes: sorted u16 src list + rs/deg.
// ---------------------------------------------------------------------------
__global__ __launch_bounds__(1024) void sortB_kernel(
    const int* __restrict__ cursor, const unsigned int* __restrict__ gbuf,
    unsigned short* __restrict__ esrc, int* __restrict__ rs,
    int* __restrict__ deg)
{
    __shared__ int hist[NPB2];
    __shared__ int sc[NPB2];
    __shared__ unsigned short sorted[CAPB];

    const int b = blockIdx.x, t = threadIdx.x;
    int cntE = cursor[b * 16];
    cntE = (cntE > CAPB) ? CAPB : cntE;
    const int gb = b * CAPB;

    if (t < NPB2) hist[t] = 0;
    __syncthreads();
    for (int i = t; i < cntE; i += 1024)
        atomicAdd(&hist[(gbuf[gb + i] >> 16) & (NPB2 - 1)], 1);
    __syncthreads();

    int hv = 0;
    if (t < NPB2) { hv = hist[t]; sc[t] = hv; }
    __syncthreads();
    for (int off = 1; off < NPB2; off <<= 1) {
        int u = 0;
        if (t < NPB2 && t >= off) u = sc[t - off];
        __syncthreads();
        if (t < NPB2) sc[t] += u;
        __syncthreads();
    }
    if (t < NPB2) {
        const int excl = sc[t] - hv;
        const int node = (b << BSH) + t;
        if (node < N_NODES) { rs[node] = gb + excl; deg[node] = hv; }
        hist[t] = excl;                 // rank cursor
    }
    __syncthreads();

    for (int i = t; i < cntE; i += 1024) {
        const unsigned v = gbuf[gb + i];
        const int slot = atomicAdd(&hist[(v >> 16) & (NPB2 - 1)], 1);
        sorted[slot] = (unsigned short)(v & 0xFFFFu);
    }
    __syncthreads();

    for (int i = t; i < cntE; i += 1024) esrc[gb + i] = sorted[i];
}

// ---------------------------------------------------------------------------
// Gather + dual-GEMM + ReLU (r13 structure + half2 edge-pairing).
// 512 thr = 8 waves share one Ut/Vt; wave per node.
// Lanes 0-31 take edge j (features 2l,2l+1 via half2), lanes 32-63 edge j+1;
// one wave-load covers 2 rows. Final shfl_xor(32) merges the halves.
// ---------------------------------------------------------------------------
__global__ __launch_bounds__(512, 8) void gather_gemm_f16_kernel(
    const float* __restrict__ x, const _Float16* __restrict__ xh,
    const int* __restrict__ rs, const int* __restrict__ deg,
    const unsigned short* __restrict__ esrc,
    const float* __restrict__ U, const float* __restrict__ V,
    float* __restrict__ out)
{
    __shared__ float Ut[D][D + 1];
    __shared__ float Vt[D][D + 1];
    __shared__ float rows[8][2][D];

    const int t = threadIdx.x, o = t & 63, w = t >> 6;

    for (int i = t; i < D * D; i += 512) {
        Ut[i & 63][i >> 6] = U[i];
        Vt[i & 63][i >> 6] = V[i];
    }
    __syncthreads();

    const int n = blockIdx.x * 8 + w;   // grid exactly N_NODES/8
    const int rowoff = n * D + o;

    rows[w][0][o] = x[rowoff];

    const int beg = rs[n];
    int dg = deg[n];
    dg = (dg > 64) ? 64 : dg;
    const int vidx = (int)esrc[beg + ((o < dg) ? o : 0)];

    const int hsel = o >> 5;            // 0: edge j, 1: edge j+1
    const int fo2  = (o & 31) * 2;      // feature pair base

    union H2 { unsigned u; _Float16 h[2]; };
    float a0 = 0.f, a1 = 0.f;

    int j = 0;
    for (; j + 8 <= dg; j += 8) {       // 4 independent 2-row wave-loads
        const int sA = __shfl(vidx, j + 0 + hsel);
        const int sB = __shfl(vidx, j + 2 + hsel);
        const int sC = __shfl(vidx, j + 4 + hsel);
        const int sD = __shfl(vidx, j + 6 + hsel);
        H2 pA, pB, pC, pD;
        pA.u = *reinterpret_cast<const unsigned*>(xh + sA * D + fo2);
        pB.u = *reinterpret_cast<const unsigned*>(xh + sB * D + fo2);
        pC.u = *reinterpret_cast<const unsigned*>(xh + sC * D + fo2);
        pD.u = *reinterpret_cast<const unsigned*>(xh + sD * D + fo2);
        a0 += ((float)pA.h[0] + (float)pB.h[0])
            + ((float)pC.h[0] + (float)pD.h[0]);
        a1 += ((float)pA.h[1] + (float)pB.h[1])
            + ((float)pC.h[1] + (float)pD.h[1]);
    }
    for (; j + 2 <= dg; j += 2) {
        const int s = __shfl(vidx, j + hsel);
        H2 p;
        p.u = *reinterpret_cast<const unsigned*>(xh + s * D + fo2);
        a0 += (float)p.h[0];
        a1 += (float)p.h[1];
    }
    if (j < dg) {                       // odd tail: lanes<32 only
        const int s = __shfl(vidx, j);
        if (o < 32) {
            H2 p;
            p.u = *reinterpret_cast<const unsigned*>(xh + s * D + fo2);
            a0 += (float)p.h[0];
            a1 += (float)p.h[1];
        }
    }
    a0 += __shfl_xor(a0, 32);
    a1 += __shfl_xor(a1, 32);
    if (o < 32) {
        rows[w][1][fo2 + 0] = a0;
        rows[w][1][fo2 + 1] = a1;
    }
    // wave-private LDS rows: in-wave ordering, no block barrier needed.

    float sum = 0.f;
    #pragma unroll
    for (int k4 = 0; k4 < D / 4; ++k4) {
        const int k = k4 * 4;
        const float4 xq = *reinterpret_cast<const float4*>(&rows[w][0][k]);
        const float4 aq = *reinterpret_cast<const float4*>(&rows[w][1][k]);
        sum += xq.x * Ut[k + 0][o] + aq.x * Vt[k + 0][o];
        sum += xq.y * Ut[k + 1][o] + aq.y * Vt[k + 1][o];
        sum += xq.z * Ut[k + 2][o] + aq.z * Vt[k + 2][o];
        sum += xq.w * Ut[k + 3][o] + aq.w * Vt[k + 3][o];
    }
    out[rowoff] = fmaxf(sum, 0.f);
}

// ---------------------------------------------------------------------------
// Mid fallback (r12): 64-cap bucket fill + f32 gather.
// ---------------------------------------------------------------------------
__global__ __launch_bounds__(256) void fill_only_kernel(
    const int* __restrict__ src, const int* __restrict__ dst,
    int* __restrict__ deg, unsigned short* __restrict__ esrc)
{
    const int e = blockIdx.x * 256 + threadIdx.x;
    if (e < N_EDGES) {
        const int d = dst[e];
        const int s = src[e];
        const int sl = atomicAdd(&deg[d], 1);
        if (sl < CAP) esrc[(d << 6) + sl] = (unsigned short)s;
    }
}

__global__ __launch_bounds__(512, 8) void bucket_gather_gemm_kernel(
    const float* __restrict__ x, const int* __restrict__ deg,
    const unsigned short* __restrict__ esrc,
    const float* __restrict__ U, const float* __restrict__ V,
    float* __restrict__ out)
{
    __shared__ float Ut[D][D + 1];
    __shared__ float Vt[D][D + 1];
    __shared__ float rows[8][2][D];

    const int t = threadIdx.x, o = t & 63, w = t >> 6;

    for (int i = t; i < D * D; i += 512) {
        Ut[i & 63][i >> 6] = U[i];
        Vt[i & 63][i >> 6] = V[i];
    }
    __syncthreads();

    const int n = blockIdx.x * 8 + w;
    const int rowoff = n * D + o;
    rows[w][0][o] = x[rowoff];

    int dg = deg[n];
    dg = (dg > CAP) ? CAP : dg;
    const int vidx = (int)esrc[(n << 6) + ((o < dg) ? o : 0)];

    float acc = 0.f;
    int j = 0;
    for (; j + 4 <= dg; j += 4) {
        const int s0 = __shfl(vidx, j + 0), s1 = __shfl(vidx, j + 1);
        const int s2 = __shfl(vidx, j + 2), s3 = __shfl(vidx, j + 3);
        acc += x[s0 * D + o] + x[s1 * D + o] + x[s2 * D + o] + x[s3 * D + o];
    }
    for (; j < dg; ++j) {
        const int s = __shfl(vidx, j);
        acc += x[s * D + o];
    }
    rows[w][1][o] = acc;

    float sum = 0.f;
    #pragma unroll
    for (int k4 = 0; k4 < D / 4; ++k4) {
        const int k = k4 * 4;
        const float4 xq = *reinterpret_cast<const float4*>(&rows[w][0][k]);
        const float4 aq = *reinterpret_cast<const float4*>(&rows[w][1][k]);
        sum += xq.x * Ut[k + 0][o] + aq.x * Vt[k + 0][o];
        sum += xq.y * Ut[k + 1][o] + aq.y * Vt[k + 1][o];
        sum += xq.z * Ut[k + 2][o] + aq.z * Vt[k + 2][o];
        sum += xq.w * Ut[k + 3][o] + aq.w * Vt[k + 3][o];
    }
    out[rowoff] = fmaxf(sum, 0.f);
}

// ---------------------------------------------------------------------------
// Last-resort fallback: atomic scatter + separate GEMM (no ws needed).
// ---------------------------------------------------------------------------
__global__ __launch_bounds__(256) void scatter_add_kernel(
    const float* __restrict__ x, const int* __restrict__ src,
    const int* __restrict__ dst, float* agg)
{
    const int tid = blockIdx.x * 256 + threadIdx.x;
    const int e = tid >> 4;
    const int qq = (tid & 15) << 2;
    const int s = src[e];
    const int d = dst[e];
    const float4 v = *reinterpret_cast<const float4*>(x + s * D + qq);
    float* a = agg + d * D + qq;
    unsafeAtomicAdd(a + 0, v.x);
    unsafeAtomicAdd(a + 1, v.y);
    unsafeAtomicAdd(a + 2, v.z);
    unsafeAtomicAdd(a + 3, v.w);
}

__global__ __launch_bounds__(256) void gemm_relu_kernel(
    const float* __restrict__ x, const float* agg,
    const float* __restrict__ U, const float* __restrict__ V,
    float* out)
{
    __shared__ float Ut[D][D + 1];
    __shared__ float Vt[D][D + 1];
    __shared__ float xs[4][D][4];
    __shared__ float as[4][D][4];

    const int t = threadIdx.x, o = t & 63, w = t >> 6;

    for (int i = t; i < D * D; i += 256) {
        Ut[i & 63][i >> 6] = U[i];
        Vt[i & 63][i >> 6] = V[i];
    }
    __syncthreads();

    const int nb = blockIdx.x * 16 + w * 4;
    #pragma unroll
    for (int j = 0; j < 4; ++j) {
        const int n = nb + j;
        xs[w][o][j] = x[n * D + o];
        as[w][o][j] = agg[n * D + o];
    }

    float acc0 = 0.f, acc1 = 0.f, acc2 = 0.f, acc3 = 0.f;
    #pragma unroll 16
    for (int k = 0; k < D; ++k) {
        const float u = Ut[k][o];
        const float v = Vt[k][o];
        const float4 xv = *reinterpret_cast<const float4*>(&xs[w][k][0]);
        const float4 av = *reinterpret_cast<const float4*>(&as[w][k][0]);
        acc0 += u * xv.x + v * av.x;
        acc1 += u * xv.y + v * av.y;
        acc2 += u * xv.z + v * av.z;
        acc3 += u * xv.w + v * av.w;
    }

    out[(nb + 0) * D + o] = fmaxf(acc0, 0.f);
    out[(nb + 1) * D + o] = fmaxf(acc1, 0.f);
    out[(nb + 2) * D + o] = fmaxf(acc2, 0.f);
    out[(nb + 3) * D + o] = fmaxf(acc3, 0.f);
}

extern "C" void kernel_launch(void* const* d_in, const int* in_sizes, int n_in,
                              void* d_out, int out_size, void* d_ws, size_t ws_size,
                              hipStream_t stream) {
    const float* x   = (const float*)d_in[0];
    const int*   src = (const int*)d_in[1];
    const int*   dst = (const int*)d_in[2];
    const float* U   = (const float*)d_in[3];
    const float* V   = (const float*)d_in[4];
    float* out = (float*)d_out;

    // full ws layout (int units):
    //   cursor [196*16] | gbuf u32 [196*5888] | rs [50000] | deg [50000] |
    //   esrc u16 [196*5888] | xh fp16 [3.2M]              (~13.7 MiB)
    const size_t cur_off = 0;
    const size_t gb_off  = (size_t)NBK * 16;
    const size_t rs_off  = gb_off + (size_t)NBK * CAPB;
    const size_t dg_off  = rs_off + N_NODES;
    const size_t es_off  = dg_off + N_NODES;
    const size_t xh_off  = es_off + (size_t)NBK * CAPB / 2;
    const size_t full_bytes = (xh_off + (size_t)N_NODES * D / 2) * sizeof(int);

    // mid (r12) layout: deg[50000] | esrc u16[50000*64]
    const size_t m_es_off = (size_t)N_NODES;
    const size_t mid_bytes = (m_es_off + (size_t)N_NODES * CAP / 2) * sizeof(int);

    if (ws_size >= full_bytes) {
        int* wsi = (int*)d_ws;
        int* cursor = wsi + cur_off;
        unsigned int* gbuf = (unsigned int*)(wsi + gb_off);
        int* rs  = wsi + rs_off;
        int* deg = wsi + dg_off;
        unsigned short* esrc = (unsigned short*)(wsi + es_off);
        _Float16* xh = (_Float16*)(wsi + xh_off);

        hipMemsetAsync(cursor, 0, (size_t)NBK * 16 * sizeof(int), stream);
        binA_cvt_kernel<<<ABLK + CVT_BLOCKS, 256, 0, stream>>>(
            x, xh, src, dst, cursor, gbuf);
        sortB_kernel<<<NBK, 1024, 0, stream>>>(cursor, gbuf, esrc, rs, deg);
        gather_gemm_f16_kernel<<<N_NODES / 8, 512, 0, stream>>>(
            x, xh, rs, deg, esrc, U, V, out);
    } else if (ws_size >= mid_bytes) {
        int* wsi = (int*)d_ws;
        int* deg = wsi;
        unsigned short* esrc = (unsigned short*)(wsi + m_es_off);

        hipMemsetAsync(deg, 0, (size_t)N_NODES * sizeof(int), stream);
        fill_only_kernel<<<(N_EDGES + 255) / 256, 256, 0, stream>>>(
            src, dst, deg, esrc);
        bucket_gather_gemm_kernel<<<N_NODES / 8, 512, 0, stream>>>(
            x, deg, esrc, U, V, out);
    } else {
        const size_t agg_bytes = (size_t)N_NODES * D * sizeof(float);
        float* agg = (ws_size >= agg_bytes) ? (float*)d_ws : out;
        hipMemsetAsync(agg, 0, agg_bytes, stream);
        scatter_add_kernel<<<(N_EDGES * 16) / 256, 256, 0, stream>>>(x, src, dst, agg);
        gemm_relu_kernel<<<N_NODES / 16, 256, 0, stream>>>(x, agg, U, V, out);
    }
}